// Round 13
// baseline (129.111 us; speedup 1.0000x reference)
//
#include <hip/hip_runtime.h>
#include <hip/hip_bf16.h>
#include <math.h>

constexpr int kB = 128;
constexpr int kT = 256;
constexpr int kC = 384;
constexpr int kH = 64;

using bf16x8 = __attribute__((ext_vector_type(8))) short;  // 8 bf16 = 4 VGPRs
using f32x4  = __attribute__((ext_vector_type(4))) float;

union BF8 { bf16x8 v; __hip_bfloat162 h[4]; };
union BF4 { short4 s; __hip_bfloat162 h[2]; };

__device__ inline bf16x8 cvt8(float4 a, float4 b) {
    BF8 u;
    u.h[0] = __float22bfloat162_rn(float2{a.x, a.y});
    u.h[1] = __float22bfloat162_rn(float2{a.z, a.w});
    u.h[2] = __float22bfloat162_rn(float2{b.x, b.y});
    u.h[3] = __float22bfloat162_rn(float2{b.z, b.w});
    return u.v;
}
__device__ inline short4 cvt4(float4 a) {
    BF4 u;
    u.h[0] = __float22bfloat162_rn(float2{a.x, a.y});
    u.h[1] = __float22bfloat162_rn(float2{a.z, a.w});
    return u.s;
}
__device__ inline short bf1(float f) {
    __hip_bfloat16 h = __float2bfloat16(f);
    return *(short*)&h;
}

// ---------------------------------------------------------------------------
// Kernel 0: Wt[n][k] bf16, n in [0,192) = (w*64+h), k in [0,384).
// Wk rows pre-scaled by 384^-0.5 * log2(e) (exp2-domain softmax, R10 win).
// ---------------------------------------------------------------------------
__global__ void prep_kernel(const float* __restrict__ Wq,
                            const float* __restrict__ Wk,
                            const float* __restrict__ Wv,
                            __hip_bfloat16* __restrict__ Wt) {
    int idx = blockIdx.x * 256 + threadIdx.x;     // [0, 192*384)
    int n = idx / kC, c = idx % kC;
    int w = n >> 6, h = n & 63;
    const float* W = (w == 0) ? Wq : (w == 1) ? Wk : Wv;
    float val = W[c * kH + h];
    if (w == 1) val *= 0.07362222374744683f;      // 384^-0.5 * log2(e)
    Wt[idx] = __float2bfloat16(val);
}

// ---------------------------------------------------------------------------
// Fused kernel — destaged phase 1, take 2 (R8 concept, R8's failure fixed).
// R8's counters (MfmaUtil 4.5, VALU 6.9, VGPR 88) showed the per-step loads
// were SERIALIZED (load->wait->MFMA chains, ~14 round-trips/step). Fix:
//  - All 12 B-fragment loads batched into named regs pb[12] (full unroll,
//    static indices) BEFORE the MFMA cluster -> one wait, 12 in flight.
//  - A-tile prefetched one step ahead into pa[2][4] (ping-pong, s&1 static
//    under full unroll). ISSUE ORDER: B(s) first, THEN A(s+1) — vmcnt is
//    in-order, so waiting for pb[] must not drain the younger A prefetch;
//    the A loads stay in flight across the entire step's MFMAs.
//  - B is the same 12 KB/step for every wave -> L1-hot after wave 0.
// Phase 1 has ZERO barriers, ZERO LDS staging; per-wave rows (heavy 32,
// light 16), acc[2][12] in AGPRs; dead-K skip for heavy waves 0-3 (j 4..7).
// Register budget ~210 < 256 at (512,2) — no R7-style cap, no spill.
// Epilogue (R8, verified) scatters into Qs/Ks/VTs homes; ONE barrier;
// phase 2 = R12's batch softmax + exp2 + hoisted-V + Pb round-trip
// (Pb now a dedicated 18 KB buffer — the dead-As trick has no As).
// LDS: 36864+18432+33792+18432 = 107,520 B, 1 block/CU.
// Ledger: staged monolith plateau 109.9-110.6 (R10/R12); more waves x,
// split x, BK=64 x, caps<256 fatal, 2-deep ~0, serialized-destaged x (R8).
// ---------------------------------------------------------------------------
__global__ __launch_bounds__(512, 2) void fused_kernel(
    const float* __restrict__ x, const __hip_bfloat16* __restrict__ Wt,
    float* __restrict__ out)
{
    __shared__ short Qs[256 * 72];      // [s][h]
    __shared__ short Ks[128 * 72];      // [t-t0][h]
    __shared__ short VTs[64 * 264];     // [h][s]
    __shared__ short Pbuf[8 * 1152];    // per-wave 16x72 bf16 P tile

    const int bid  = blockIdx.x;
    const int b    = ((bid >> 4) << 3) | (bid & 7);   // batch
    const int half = ((bid >> 3) & 1) ^ 1;            // heavy (1) first
    const int t0   = half * 128;

    const int tid  = threadIdx.x;
    const int wave = tid >> 6, lane = tid & 63;
    const int m16  = lane & 15, quad = lane >> 4;
    const short* wt = (const short*)Wt;
    const float* xb = x + (size_t)b * kT * kC;

    // ---------------- Phase 1: destaged projection (no barriers) -----------
    const int wbase = half ? wave * 32 : wave * 16;
    const float* xr0 = xb + (size_t)(wbase + m16) * kC;
    const float* xr1 = xb + (size_t)(wbase + 16 + m16) * kC;
    const bool loW = (wave < 4);       // heavy dead-K group (rows < 128)

    f32x4 acc[2][12];
#pragma unroll
    for (int mt = 0; mt < 2; ++mt)
#pragma unroll
        for (int j = 0; j < 12; ++j) acc[mt][j] = f32x4{0.f, 0.f, 0.f, 0.f};

    float4 pa[2][4];                   // A prefetch ping-pong (static idx)
    bf16x8 pb[12];                     // B fragments, current step

    // prologue: A(0) into pa[0]
    {
        pa[0][0] = *(const float4*)(xr0 + quad * 8);
        pa[0][1] = *(const float4*)(xr0 + quad * 8 + 4);
        if (half) {
            pa[0][2] = *(const float4*)(xr1 + quad * 8);
            pa[0][3] = *(const float4*)(xr1 + quad * 8 + 4);
        }
    }

#pragma unroll
    for (int s = 0; s < 12; ++s) {
        const int cur = s & 1;                     // compile-time (unrolled)
        const int k0  = s * 32 + quad * 8;

        // B(s) loads FIRST (oldest in vmcnt order -> MFMA waits drain only
        // these, never the A prefetch issued after)
#pragma unroll
        for (int j = 0; j < 12; ++j) {
            const bool skip = half && loW && (j >= 4) && (j < 8);
            if (!skip)
                pb[j] = *(const bf16x8*)(wt + (size_t)(j * 16 + m16) * kC + k0);
        }
        // A(s+1) prefetch AFTER B — stays in flight across this step
        if (s < 11) {
            const int k1 = (s + 1) * 32 + quad * 8;
            pa[cur ^ 1][0] = *(const float4*)(xr0 + k1);
            pa[cur ^ 1][1] = *(const float4*)(xr0 + k1 + 4);
            if (half) {
                pa[cur ^ 1][2] = *(const float4*)(xr1 + k1);
                pa[cur ^ 1][3] = *(const float4*)(xr1 + k1 + 4);
            }
        }

        // cvt A(s) (loaded a full step ago — no wait) + MFMA cluster
        bf16x8 af0 = cvt8(pa[cur][0], pa[cur][1]);
        bf16x8 af1;
        if (half) af1 = cvt8(pa[cur][2], pa[cur][3]);
#pragma unroll
        for (int j = 0; j < 12; ++j) {
            const bool skip = half && loW && (j >= 4) && (j < 8);
            if (!skip) {
                acc[0][j] = __builtin_amdgcn_mfma_f32_16x16x32_bf16(
                    af0, pb[j], acc[0][j], 0, 0, 0);
                if (half)
                    acc[1][j] = __builtin_amdgcn_mfma_f32_16x16x32_bf16(
                        af1, pb[j], acc[1][j], 0, 0, 0);
            }
        }
    }

    // epilogue (R8, verified): C-layout -> LDS homes
#pragma unroll
    for (int mt = 0; mt < 2; ++mt) {
        if (mt == 0 || half) {
            const int mbase = wbase + mt * 16 + quad * 4;
#pragma unroll
            for (int j = 0; j < 12; ++j) {
                const int w = j >> 2;                  // 0=q, 1=k, 2=v
                const int h = (j & 3) * 16 + m16;
                const bool skip = half && loW && (j >= 4) && (j < 8);
                if (!skip) {
                    if (w == 2) {
                        float4 f = make_float4(acc[mt][j][0], acc[mt][j][1],
                                               acc[mt][j][2], acc[mt][j][3]);
                        *(short4*)&VTs[h * 264 + mbase] = cvt4(f);
                    } else if (w == 1) {
                        if ((mbase >> 7) == half) {    // rows [t0, t0+128)
#pragma unroll
                            for (int r = 0; r < 4; ++r)
                                Ks[(mbase + r - t0) * 72 + h] = bf1(acc[mt][j][r]);
                        }
                    } else {
#pragma unroll
                        for (int r = 0; r < 4; ++r)
                            Qs[(mbase + r) * 72 + h] = bf1(acc[mt][j][r]);
                    }
                }
            }
        }
    }
    __syncthreads();   // THE phase boundary: Qs/Ks/VTs all visible

    // -------- Phase 2: attention, BATCH softmax (barrier-free, R12) --------
    const int wband = t0 + wave * 16;              // this wave's t-band
    short* Pb = &Pbuf[wave * 1152];                // 16x72 bf16 per wave

    const bf16x8 ka0 = *(const bf16x8*)&Ks[(wave * 16 + m16) * 72 + quad * 8];
    const bf16x8 ka1 = *(const bf16x8*)&Ks[(wave * 16 + m16) * 72 + quad * 8 + 32];

    const int ilast = wband >> 6;                  // wave-uniform
    const int jmaxd = wave & 3;                    // diag-tile jmax

    // all S' tiles in registers: S[i][j][r], s = i*64+j*16+quad*4+r, t = m16
    f32x4 S[4][4];
    const f32x4 Z = f32x4{0.f, 0.f, 0.f, 0.f};
#pragma unroll
    for (int i = 0; i < 4; ++i)
#pragma unroll
        for (int j = 0; j < 4; ++j) S[i][j] = Z;

    __builtin_amdgcn_s_setprio(1);
#pragma unroll
    for (int i = 0; i < 4; ++i) {
        if (i <= ilast) {
#pragma unroll
            for (int j = 0; j < 4; ++j) {
                if (i < ilast || j <= jmaxd) {
                    const int s = i * 64 + j * 16 + m16;
                    bf16x8 qb0 = *(const bf16x8*)&Qs[s * 72 + quad * 8];
                    bf16x8 qb1 = *(const bf16x8*)&Qs[s * 72 + quad * 8 + 32];
                    S[i][j] = __builtin_amdgcn_mfma_f32_16x16x32_bf16(qb0, ka0, S[i][j], 0, 0, 0);
                    S[i][j] = __builtin_amdgcn_mfma_f32_16x16x32_bf16(qb1, ka1, S[i][j], 0, 0, 0);
                }
            }
        }
    }
    __builtin_amdgcn_s_setprio(0);

    // diagonal mask on tile (ilast, jmaxd): s > t -> -inf   (static indices)
#pragma unroll
    for (int i = 0; i < 4; ++i)
#pragma unroll
        for (int j = 0; j < 4; ++j)
            if (i == ilast && j == jmaxd) {
#pragma unroll
                for (int r = 0; r < 4; ++r)
                    if (quad * 4 + r > m16) S[i][j][r] = -INFINITY;
            }

    // ONE global max over the whole row (t = wband + m16); log2 domain
    float rm = -INFINITY;
#pragma unroll
    for (int i = 0; i < 4; ++i)
#pragma unroll
        for (int j = 0; j < 4; ++j)
            if (i <= ilast && (i < ilast || j <= jmaxd))
#pragma unroll
                for (int r = 0; r < 4; ++r) rm = fmaxf(rm, S[i][j][r]);
    rm = fmaxf(rm, __shfl_xor(rm, 16, 64));
    rm = fmaxf(rm, __shfl_xor(rm, 32, 64));

    // ONE exp2 pass in place + row sum (exp2f -> single v_exp_f32)
    float l_ = 0.f;
#pragma unroll
    for (int i = 0; i < 4; ++i)
#pragma unroll
        for (int j = 0; j < 4; ++j)
            if (i <= ilast && (i < ilast || j <= jmaxd))
#pragma unroll
                for (int r = 0; r < 4; ++r) {
                    const float e = exp2f(S[i][j][r] - rm);
                    S[i][j][r] = e;
                    l_ += e;
                }
    l_ += __shfl_xor(l_, 16, 64);
    l_ += __shfl_xor(l_, 32, 64);

    // PV: per i-tile — V-fragment ds_reads issued FIRST, then P pack -> Pb
    // -> A-fragment read, then 8 MFMAs.
    f32x4 O[4];
#pragma unroll
    for (int i = 0; i < 4; ++i) O[i] = f32x4{0.f, 0.f, 0.f, 0.f};

#pragma unroll
    for (int i = 0; i < 4; ++i) {
        if (i <= ilast) {
            bf16x8 vb[4][2];
#pragma unroll
            for (int ht = 0; ht < 4; ++ht) {
                vb[ht][0] = *(const bf16x8*)&VTs[(ht * 16 + m16) * 264 + i * 64 + quad * 8];
                vb[ht][1] = *(const bf16x8*)&VTs[(ht * 16 + m16) * 264 + i * 64 + quad * 8 + 32];
            }
#pragma unroll
            for (int j = 0; j < 4; ++j)
#pragma unroll
                for (int p = 0; p < 2; ++p) {
                    __hip_bfloat162 w = __float22bfloat162_rn(
                        float2{S[i][j][2 * p], S[i][j][2 * p + 1]});
                    *(__hip_bfloat162*)&Pb[m16 * 72 + j * 16 + quad * 4 + 2 * p] = w;
                }
            bf16x8 pf0 = *(const bf16x8*)&Pb[m16 * 72 + quad * 8];
            bf16x8 pf1 = *(const bf16x8*)&Pb[m16 * 72 + quad * 8 + 32];

            __builtin_amdgcn_s_setprio(1);
#pragma unroll
            for (int ht = 0; ht < 4; ++ht) {
                O[ht] = __builtin_amdgcn_mfma_f32_16x16x32_bf16(pf0, vb[ht][0], O[ht], 0, 0, 0);
                O[ht] = __builtin_amdgcn_mfma_f32_16x16x32_bf16(pf1, vb[ht][1], O[ht], 0, 0, 0);
            }
            __builtin_amdgcn_s_setprio(0);
        }
    }

    // epilogue: 1/l broadcast from t=m16 holders, scale, store
    float lbc[4];
#pragma unroll
    for (int r = 0; r < 4; ++r)
        lbc[r] = __shfl(l_, (quad << 4) | (quad * 4 + r), 64);
#pragma unroll
    for (int r = 0; r < 4; ++r) {
        const float inv = 1.f / lbc[r];
        const size_t row = (size_t)(b * kT + wband + quad * 4 + r);
#pragma unroll
        for (int ht = 0; ht < 4; ++ht)
            out[row * kH + ht * 16 + m16] = O[ht][r] * inv;
    }
}

// ---------------------------------------------------------------------------
extern "C" void kernel_launch(void* const* d_in, const int* in_sizes, int n_in,
                              void* d_out, int out_size, void* d_ws, size_t ws_size,
                              hipStream_t stream) {
    const float* x  = (const float*)d_in[0];
    const float* Wq = (const float*)d_in[1];
    const float* Wk = (const float*)d_in[2];
    const float* Wv = (const float*)d_in[3];
    float* out = (float*)d_out;

    __hip_bfloat16* Wt = (__hip_bfloat16*)d_ws;    // 147 KB [n][k]

    prep_kernel<<<(192 * kC) / 256, 256, 0, stream>>>(Wq, Wk, Wv, Wt);
    fused_kernel<<<dim3(256), 512, 0, stream>>>(x, Wt, out);
}

// Round 14
// 106.422 us; speedup vs baseline: 1.2132x; 1.2132x over previous
//
#include <hip/hip_runtime.h>
#include <hip/hip_bf16.h>
#include <math.h>

constexpr int kB = 128;
constexpr int kT = 256;
constexpr int kC = 384;
constexpr int kH = 64;

using bf16x8 = __attribute__((ext_vector_type(8))) short;  // 8 bf16 = 4 VGPRs
using f32x4  = __attribute__((ext_vector_type(4))) float;

union BF4 { short4 s; __hip_bfloat162 h[2]; };

__device__ inline short4 cvt4(float4 a) {
    BF4 u;
    u.h[0] = __float22bfloat162_rn(float2{a.x, a.y});
    u.h[1] = __float22bfloat162_rn(float2{a.z, a.w});
    return u.s;
}
__device__ inline short bf1(float f) {
    __hip_bfloat16 h = __float2bfloat16(f);
    return *(short*)&h;
}

// ---------------------------------------------------------------------------
// Kernel 0: Wt[n][k] bf16, n in [0,192) = (w*64+h), k in [0,384).
// Wk rows pre-scaled by 384^-0.5 * log2(e) (exp2-domain softmax, R10 win).
// ---------------------------------------------------------------------------
__global__ void prep_kernel(const float* __restrict__ Wq,
                            const float* __restrict__ Wk,
                            const float* __restrict__ Wv,
                            __hip_bfloat16* __restrict__ Wt) {
    int idx = blockIdx.x * 256 + threadIdx.x;     // [0, 192*384)
    int n = idx / kC, c = idx % kC;
    int w = n >> 6, h = n & 63;
    const float* W = (w == 0) ? Wq : (w == 1) ? Wk : Wv;
    float val = W[c * kH + h];
    if (w == 1) val *= 0.07362222374744683f;      // 384^-0.5 * log2(e)
    Wt[idx] = __float2bfloat16(val);
}

// ---------------------------------------------------------------------------
// Fused kernel — R12 staged structure (best family: dur 109.9-110.6) with
// BALANCED even/odd t-band interleave replacing the heavy/light row split.
// Rationale: at 1 block/CU, dur = the slowest block. Old split: heavy block
// = M-256 phase 1 + phase-2 bands 8-15 (28 i-tile units); light = M-128 +
// bands 0-7 (12 units) then idles. New: BOTH blocks do the full 256-row Q/V
// projection (pair makespan unchanged — that was the heavy block's load) and
// each owns t-bands of one parity (band = 2*wave + blk): 20 units each,
// -29% phase-2 on the critical blocks. K work split by row-tile parity
// ((mt&1)==blk, same chip-wide FLOPs); K epilogue writes band slot
// wm*4+(mt>>1) so phase 2's Ks[wave*16+m16] read is unchanged.
// Also keeps: exp2-domain softmax, batch softmax (S[4][4] in regs), no
// step-11 barrier, hoisted V-fragment reads, setprio, XCD pair swizzle.
// Ledger: more waves x, split x, destaged x (R8/R13), BK=64 x, caps<256
// fatal, 2-deep ~0.
// ---------------------------------------------------------------------------
__global__ __launch_bounds__(512, 2) void fused_kernel(
    const float* __restrict__ x, const __hip_bfloat16* __restrict__ Wt,
    float* __restrict__ out)
{
    __shared__ short Qs[256 * 72];      // [s][h]
    __shared__ short Ks[128 * 72];      // [band-slot rows][h]
    __shared__ short VTs[64 * 264];     // [h][s]
    __shared__ short As[2][256 * 36];   // x tile bf16 [m][kk], stride 36
    __shared__ short Bs[2][192 * 36];   // Wt tile    [n][kk], stride 36

    const int bid  = blockIdx.x;
    const int b    = ((bid >> 4) << 3) | (bid & 7);   // batch
    const int blk  = (bid >> 3) & 1;                  // band parity owner

    const int tid  = threadIdx.x;
    const int wave = tid >> 6, lane = tid & 63;
    const int m16  = lane & 15, quad = lane >> 4;
    const int wm = wave & 1, wn = wave >> 1;       // m-half, 3-n-tile slice
    const short* wt = (const short*)Wt;
    const float* xb = x + (size_t)b * kT * kC;

    // ---------------- Phase 1: projection (symmetric, M=256) --------------
    const int arow = tid >> 1, acol = (tid & 1) * 16;

    float4 la[4]; bf16x8 lb0, lb1;
    auto glod = [&](int k0) {
#pragma unroll
        for (int i = 0; i < 4; ++i)
            la[i] = *(const float4*)(xb + (size_t)arow * kC + k0 + acol + 4 * i);
        {
            int n = tid >> 2, kk = (tid & 3) * 8;
            lb0 = *(const bf16x8*)(wt + (size_t)n * kC + k0 + kk);
        }
        if (tid < 256) {
            int c = tid + 512;
            int n = c >> 2, kk = (c & 3) * 8;
            lb1 = *(const bf16x8*)(wt + (size_t)n * kC + k0 + kk);
        }
    };
    auto swr = [&](int d) {
#pragma unroll
        for (int i = 0; i < 4; ++i)
            *(short4*)&As[d][arow * 36 + acol + 4 * i] = cvt4(la[i]);
        {
            int n = tid >> 2, kk = (tid & 3) * 8;
            *(bf16x8*)&Bs[d][n * 36 + kk] = lb0;
        }
        if (tid < 256) {
            int c = tid + 512;
            int n = c >> 2, kk = (c & 3) * 8;
            *(bf16x8*)&Bs[d][n * 36 + kk] = lb1;
        }
    };

    // is this wave's j-th n-tile a K tile? (n-tiles 4..7 are K)
    bool isK[3];
#pragma unroll
    for (int j = 0; j < 3; ++j) {
        const int nt = wn * 3 + j;
        isK[j] = (nt >= 4) && (nt < 8);
    }

    f32x4 acc[8][3];
#pragma unroll
    for (int mt = 0; mt < 8; ++mt)
#pragma unroll
        for (int j = 0; j < 3; ++j) acc[mt][j] = f32x4{0.f, 0.f, 0.f, 0.f};

    glod(0);
    swr(0);
    __syncthreads();

    for (int s = 0; s < 12; ++s) {
        const int d = s & 1;
        if (s < 11) glod((s + 1) * 32);            // next tile in flight

        {
            bf16x8 af[8];
#pragma unroll
            for (int mt = 0; mt < 8; ++mt)
                af[mt] = *(const bf16x8*)&As[d][(wm * 128 + mt * 16 + m16) * 36 + quad * 8];
#pragma unroll
            for (int j = 0; j < 3; ++j) {
                const bf16x8 bfr =
                    *(const bf16x8*)&Bs[d][((wn * 3 + j) * 16 + m16) * 36 + quad * 8];
#pragma unroll
                for (int mt = 0; mt < 8; ++mt) {
                    // K tiles: only row-tiles of our parity (band = wm*8+mt,
                    // parity = mt&1) are kept by the epilogue -> skip others
                    if (!isK[j] || ((mt & 1) == blk))
                        acc[mt][j] = __builtin_amdgcn_mfma_f32_16x16x32_bf16(
                            af[mt], bfr, acc[mt][j], 0, 0, 0);
                }
            }
        }

        if (s < 11) {
            swr(d ^ 1);
            __syncthreads();       // step 11: no barrier needed (no swr after;
        }                          // phase boundary below re-fences)
    }

    // epilogue: C-layout (col = m16 in-tile, rows = quad*4+r) -> LDS homes
#pragma unroll
    for (int mt = 0; mt < 8; ++mt) {
        const int mbase = wm * 128 + mt * 16 + quad * 4;
#pragma unroll
        for (int j = 0; j < 3; ++j) {
            const int nt = wn * 3 + j;             // n-tile 0..11
            const int w  = nt >> 2;                // 0=q, 1=k, 2=v
            const int h  = (nt & 3) * 16 + m16;
            if (w == 2) {
                float4 f = make_float4(acc[mt][j][0], acc[mt][j][1],
                                       acc[mt][j][2], acc[mt][j][3]);
                *(short4*)&VTs[h * 264 + mbase] = cvt4(f);   // s = mbase..+3
            } else if (w == 1) {
                if ((mt & 1) == blk) {             // our parity's bands only
                    const int slot = wm * 4 + (mt >> 1);   // band>>1
#pragma unroll
                    for (int r = 0; r < 4; ++r)
                        Ks[(slot * 16 + quad * 4 + r) * 72 + h] = bf1(acc[mt][j][r]);
                }
            } else {
#pragma unroll
                for (int r = 0; r < 4; ++r)
                    Qs[(mbase + r) * 72 + h] = bf1(acc[mt][j][r]);
            }
        }
    }
    __syncthreads();   // phase boundary: Qs/Ks/VTs all visible

    // -------- Phase 2: attention, BATCH softmax (barrier-free) ----------
    const int band  = 2 * wave + blk;              // this wave's t-band index
    const int wband = band * 16;                   // t rows [wband, wband+16)
    short* Pb = &As[0][0] + wave * 1152;           // dead As: 16x72 bf16/wave

    const bf16x8 ka0 = *(const bf16x8*)&Ks[(wave * 16 + m16) * 72 + quad * 8];
    const bf16x8 ka1 = *(const bf16x8*)&Ks[(wave * 16 + m16) * 72 + quad * 8 + 32];

    const int ilast = band >> 2;                   // wave-uniform
    const int jmaxd = band & 3;                    // diag-tile jmax

    // all S' tiles in registers: S[i][j][r], s = i*64+j*16+quad*4+r, t = m16
    f32x4 S[4][4];
    const f32x4 Z = f32x4{0.f, 0.f, 0.f, 0.f};
#pragma unroll
    for (int i = 0; i < 4; ++i)
#pragma unroll
        for (int j = 0; j < 4; ++j) S[i][j] = Z;

    __builtin_amdgcn_s_setprio(1);
#pragma unroll
    for (int i = 0; i < 4; ++i) {
        if (i <= ilast) {
#pragma unroll
            for (int j = 0; j < 4; ++j) {
                if (i < ilast || j <= jmaxd) {
                    const int s = i * 64 + j * 16 + m16;
                    bf16x8 qb0 = *(const bf16x8*)&Qs[s * 72 + quad * 8];
                    bf16x8 qb1 = *(const bf16x8*)&Qs[s * 72 + quad * 8 + 32];
                    S[i][j] = __builtin_amdgcn_mfma_f32_16x16x32_bf16(qb0, ka0, S[i][j], 0, 0, 0);
                    S[i][j] = __builtin_amdgcn_mfma_f32_16x16x32_bf16(qb1, ka1, S[i][j], 0, 0, 0);
                }
            }
        }
    }
    __builtin_amdgcn_s_setprio(0);

    // diagonal mask on tile (ilast, jmaxd): s > t -> -inf   (static indices)
#pragma unroll
    for (int i = 0; i < 4; ++i)
#pragma unroll
        for (int j = 0; j < 4; ++j)
            if (i == ilast && j == jmaxd) {
#pragma unroll
                for (int r = 0; r < 4; ++r)
                    if (quad * 4 + r > m16) S[i][j][r] = -INFINITY;
            }

    // ONE global max over the whole row (t = wband + m16); log2 domain
    float rm = -INFINITY;
#pragma unroll
    for (int i = 0; i < 4; ++i)
#pragma unroll
        for (int j = 0; j < 4; ++j)
            if (i <= ilast && (i < ilast || j <= jmaxd))
#pragma unroll
                for (int r = 0; r < 4; ++r) rm = fmaxf(rm, S[i][j][r]);
    rm = fmaxf(rm, __shfl_xor(rm, 16, 64));
    rm = fmaxf(rm, __shfl_xor(rm, 32, 64));

    // ONE exp2 pass in place + row sum (exp2f -> single v_exp_f32)
    float l_ = 0.f;
#pragma unroll
    for (int i = 0; i < 4; ++i)
#pragma unroll
        for (int j = 0; j < 4; ++j)
            if (i <= ilast && (i < ilast || j <= jmaxd))
#pragma unroll
                for (int r = 0; r < 4; ++r) {
                    const float e = exp2f(S[i][j][r] - rm);
                    S[i][j][r] = e;
                    l_ += e;
                }
    l_ += __shfl_xor(l_, 16, 64);
    l_ += __shfl_xor(l_, 32, 64);

    // PV: per i-tile — V-fragment ds_reads issued FIRST, then P pack -> Pb
    // -> A-fragment read, then 8 MFMAs.
    f32x4 O[4];
#pragma unroll
    for (int i = 0; i < 4; ++i) O[i] = f32x4{0.f, 0.f, 0.f, 0.f};

#pragma unroll
    for (int i = 0; i < 4; ++i) {
        if (i <= ilast) {
            bf16x8 vb[4][2];
#pragma unroll
            for (int ht = 0; ht < 4; ++ht) {
                vb[ht][0] = *(const bf16x8*)&VTs[(ht * 16 + m16) * 264 + i * 64 + quad * 8];
                vb[ht][1] = *(const bf16x8*)&VTs[(ht * 16 + m16) * 264 + i * 64 + quad * 8 + 32];
            }
#pragma unroll
            for (int j = 0; j < 4; ++j)
#pragma unroll
                for (int p = 0; p < 2; ++p) {
                    __hip_bfloat162 w = __float22bfloat162_rn(
                        float2{S[i][j][2 * p], S[i][j][2 * p + 1]});
                    *(__hip_bfloat162*)&Pb[m16 * 72 + j * 16 + quad * 4 + 2 * p] = w;
                }
            bf16x8 pf0 = *(const bf16x8*)&Pb[m16 * 72 + quad * 8];
            bf16x8 pf1 = *(const bf16x8*)&Pb[m16 * 72 + quad * 8 + 32];

            __builtin_amdgcn_s_setprio(1);
#pragma unroll
            for (int ht = 0; ht < 4; ++ht) {
                O[ht] = __builtin_amdgcn_mfma_f32_16x16x32_bf16(pf0, vb[ht][0], O[ht], 0, 0, 0);
                O[ht] = __builtin_amdgcn_mfma_f32_16x16x32_bf16(pf1, vb[ht][1], O[ht], 0, 0, 0);
            }
            __builtin_amdgcn_s_setprio(0);
        }
    }

    // epilogue: 1/l broadcast from t=m16 holders, scale, store
    float lbc[4];
#pragma unroll
    for (int r = 0; r < 4; ++r)
        lbc[r] = __shfl(l_, (quad << 4) | (quad * 4 + r), 64);
#pragma unroll
    for (int r = 0; r < 4; ++r) {
        const float inv = 1.f / lbc[r];
        const size_t row = (size_t)(b * kT + wband + quad * 4 + r);
#pragma unroll
        for (int ht = 0; ht < 4; ++ht)
            out[row * kH + ht * 16 + m16] = O[ht][r] * inv;
    }
}

// ---------------------------------------------------------------------------
extern "C" void kernel_launch(void* const* d_in, const int* in_sizes, int n_in,
                              void* d_out, int out_size, void* d_ws, size_t ws_size,
                              hipStream_t stream) {
    const float* x  = (const float*)d_in[0];
    const float* Wq = (const float*)d_in[1];
    const float* Wk = (const float*)d_in[2];
    const float* Wv = (const float*)d_in[3];
    float* out = (float*)d_out;

    __hip_bfloat16* Wt = (__hip_bfloat16*)d_ws;    // 147 KB [n][k]

    prep_kernel<<<(192 * kC) / 256, 256, 0, stream>>>(Wq, Wk, Wv, Wt);
    fused_kernel<<<dim3(256), 512, 0, stream>>>(x, Wt, out);
}